// Round 7
// baseline (1121.620 us; speedup 1.0000x reference)
//
#include <hip/hip_runtime.h>
#include <hip/hip_bf16.h>

typedef unsigned short u16;
typedef __attribute__((ext_vector_type(8))) short bf16x8;
typedef __attribute__((ext_vector_type(2))) short s16x2;
typedef __attribute__((ext_vector_type(4))) float f32x4;

#define N_NODES 50000
#define EDGES 500000
#define WPT 31250     // 16-edge groups per type
#define EPB 2048      // persistent edge blocks per type-launch
#define NWAVES 3125   // node waves per type (50000/16)
#define NBLK 782      // ceil(NWAVES/4)
#define NBUCK 782     // dst buckets (dst>>6, 50000/64)
#define CHG 3907      // groups per XCD chunk (ceil(WPT/8))

__device__ __forceinline__ u16 f2bf(float f) {
  return __builtin_bit_cast(u16, __float2bfloat16(f));
}
__device__ __forceinline__ float bf2f(u16 u) {
  return __builtin_bit_cast(float, ((unsigned)u) << 16);
}
__device__ __forceinline__ float bfe(bf16x8 v, int j) {
  return bf2f((u16)v[j]);
}

// packed bf16 atomic add (2 values at 4B-aligned address)
__device__ __forceinline__ void pk_atomic_bf16(u16* addr, float lo, float hi) {
#if __has_builtin(__builtin_amdgcn_global_atomic_fadd_v2bf16)
  s16x2 v;
  v[0] = (short)f2bf(lo);
  v[1] = (short)f2bf(hi);
  __builtin_amdgcn_global_atomic_fadd_v2bf16(
      (__attribute__((address_space(1))) s16x2*)addr, v);
#else
  unsigned* p = (unsigned*)addr;
  unsigned old = *p, assumed;
  do {
    assumed = old;
    float l2 = bf2f((u16)(assumed & 0xffff)) + lo;
    float h2 = bf2f((u16)(assumed >> 16)) + hi;
    unsigned nv = (unsigned)f2bf(l2) | ((unsigned)f2bf(h2) << 16);
    old = atomicCAS(p, assumed, nv);
  } while (old != assumed);
#endif
}

// ---------------------------------------------------------------------------
// weights -> bf16 tables + msgX zeroing + sort-counter zeroing
// ---------------------------------------------------------------------------
__global__ __launch_bounds__(256) void prep_weights_zero(
    const float* __restrict__ Wp, const float* __restrict__ Wc,
    const float* __restrict__ W1,
    const float* __restrict__ Wrel_ab, const float* __restrict__ Wroot_ab,
    const float* __restrict__ Wrel_ba, const float* __restrict__ Wroot_ba,
    u16* __restrict__ out, u16* __restrict__ msg, int* __restrict__ cnt)
{
  if (blockIdx.x == 6826) {
    for (int i = threadIdx.x; i < 2 * NBUCK; i += 256) cnt[i] = 0;
    return;
  }
  if (blockIdx.x >= 576) {
    size_t t = (size_t)(blockIdx.x - 576) * 256 + threadIdx.x;
    bf16x8 z = {0, 0, 0, 0, 0, 0, 0, 0};
    *(bf16x8*)(msg + t * 8) = z;
    return;
  }
  int tid = blockIdx.x * 256 + threadIdx.x;  // 9*16384
  int m = tid >> 14;
  int idx = tid & 16383;
  int r = idx >> 7;
  int c = idx & 127;
  float val;
  switch (m) {
    case 0: val = Wp[r * 128 + c]; break;
    case 1: val = Wc[r * 128 + c]; break;
    case 2: val = W1[r * 384 + c]; break;
    case 3: val = W1[r * 384 + 128 + c]; break;
    case 4: val = W1[r * 384 + 256 + c]; break;
    case 5: val = Wrel_ab[r * 128 + c]; break;
    case 6: val = Wroot_ab[r * 128 + c]; break;
    case 7: val = Wrel_ba[r * 128 + c]; break;
    default: val = Wroot_ba[r * 128 + c]; break;
  }
  out[tid] = f2bf(val);
}

// ---------------------------------------------------------------------------
// Sort pass 1: dst-bucket histogram (both types), LDS pre-reduction.
// ---------------------------------------------------------------------------
__global__ __launch_bounds__(256) void edge_hist(
    const int* __restrict__ ei_ab, const int* __restrict__ ei_ba,
    int* __restrict__ cnt)   // cnt[0..NBUCK)=ab, cnt[NBUCK..2*NBUCK)=ba
{
  __shared__ int h[2 * NBUCK];
  for (int i = threadIdx.x; i < 2 * NBUCK; i += 256) h[i] = 0;
  __syncthreads();
  int total = 2 * EDGES;
  for (int idx = blockIdx.x * 256 + threadIdx.x; idx < total;
       idx += gridDim.x * 256) {
    int ty = idx >= EDGES;
    int e = idx - ty * EDGES;
    int d = ty ? ei_ba[EDGES + e] : ei_ab[EDGES + e];
    atomicAdd(&h[ty * NBUCK + (d >> 6)], 1);
  }
  __syncthreads();
  for (int i = threadIdx.x; i < 2 * NBUCK; i += 256)
    if (h[i]) atomicAdd(&cnt[i], h[i]);
}

// ---------------------------------------------------------------------------
// Sort pass 2: exclusive scan of both histograms -> ptr (single block).
// ---------------------------------------------------------------------------
__global__ __launch_bounds__(1024) void edge_scan(
    const int* __restrict__ cnt, int* __restrict__ ptr)
{
  __shared__ int s0[1024], s1[1024];
  int t = threadIdx.x;
  s0[t] = (t < NBUCK) ? cnt[t] : 0;
  s1[t] = (t < NBUCK) ? cnt[NBUCK + t] : 0;
  __syncthreads();
  for (int off = 1; off < 1024; off <<= 1) {
    int a0 = (t >= off) ? s0[t - off] : 0;
    int a1 = (t >= off) ? s1[t - off] : 0;
    __syncthreads();
    s0[t] += a0;
    s1[t] += a1;
    __syncthreads();
  }
  if (t < NBUCK) {
    ptr[t] = (t == 0) ? 0 : s0[t - 1];
    ptr[NBUCK + t] = (t == 0) ? 0 : s1[t - 1];
  }
}

// ---------------------------------------------------------------------------
// Sort pass 3: scatter edges into dst-bucket-ordered es/ed arrays.
// ---------------------------------------------------------------------------
__global__ __launch_bounds__(256) void edge_scatter_sort(
    const int* __restrict__ ei_ab, const int* __restrict__ ei_ba,
    int* __restrict__ ptr,
    int* __restrict__ es_ab, int* __restrict__ ed_ab,
    int* __restrict__ es_ba, int* __restrict__ ed_ba)
{
  int total = 2 * EDGES;
  for (int idx = blockIdx.x * 256 + threadIdx.x; idx < total;
       idx += gridDim.x * 256) {
    int ty = idx >= EDGES;
    int e = idx - ty * EDGES;
    const int* ei = ty ? ei_ba : ei_ab;
    int s = ei[e];
    int d = ei[EDGES + e];
    int pos = atomicAdd(&ptr[ty * NBUCK + (d >> 6)], 1);
    if (ty) { es_ba[pos] = s; ed_ba[pos] = d; }
    else    { es_ab[pos] = s; ed_ab[pos] = d; }
  }
}

// ---------------------------------------------------------------------------
// Fused encoder + x cast, both node sets in one dispatch (grid 2*NBLK).
// ---------------------------------------------------------------------------
__global__ __launch_bounds__(256) void encoder2(
    const float* __restrict__ xa, const float* __restrict__ xb,
    const u16* __restrict__ Wp_b, const float* __restrict__ bp,
    const u16* __restrict__ Wc_b, const float* __restrict__ bc,
    const u16* __restrict__ W1a_b, const float* __restrict__ b1,
    const u16* __restrict__ W1b_b,
    u16* __restrict__ xa_bf, u16* __restrict__ xb_bf,
    u16* __restrict__ u_a, u16* __restrict__ v_a,
    u16* __restrict__ u_b, u16* __restrict__ v_b)
{
  __shared__ u16 tile[4][2176];   // 16 x pitch 136 bf16, per wave
  int widx = threadIdx.x >> 6;
  int w = blockIdx.x * 4 + widx;         // 0 .. 2*4*NBLK-1
  int type = (w >= NBLK * 4) ? 1 : 0;
  int nw = w - type * NBLK * 4;
  if (nw >= NWAVES) nw = NWAVES - 1;     // clamp (dup work; per-wave tile, safe)
  const float* x = type ? xb : xa;
  u16* xbf_out = type ? xb_bf : xa_bf;
  u16* u_out = type ? u_b : u_a;
  u16* v_out = type ? v_b : v_a;
  int row0 = nw * 16;
  int lane = threadIdx.x & 63;
  int col = lane & 15;
  int quad = lane >> 4;
  u16* tl = tile[widx];

  bf16x8 af[4];
#pragma unroll
  for (int ks = 0; ks < 4; ks++) {
    const float* xp = x + (size_t)(row0 + col) * 128 + ks * 32 + quad * 8;
    f32x4 lo = *(const f32x4*)xp;
    f32x4 hi = *(const f32x4*)(xp + 4);
    bf16x8 o;
#pragma unroll
    for (int j = 0; j < 4; j++) {
      o[j]     = (short)f2bf(lo[j]);
      o[j + 4] = (short)f2bf(hi[j]);
    }
    af[ks] = o;
    *(bf16x8*)(xbf_out + (size_t)(row0 + col) * 128 + ks * 32 + quad * 8) = o;
  }

  f32x4 zero = {0.f, 0.f, 0.f, 0.f};

  for (int chain = 0; chain < 2; chain++) {
    const u16* Wenc = chain ? Wc_b : Wp_b;
    const float* benc = chain ? bc : bp;
    const u16* Wmix = chain ? W1b_b : W1a_b;
    const float* bmix = chain ? nullptr : b1;
    u16* outp = chain ? v_out : u_out;

    f32x4 acc[8];
#pragma unroll
    for (int nt = 0; nt < 8; nt++) acc[nt] = zero;
#pragma unroll
    for (int ks = 0; ks < 4; ks++) {
      const u16* wp = Wenc + col * 128 + ks * 32 + quad * 8;
#pragma unroll
      for (int nt = 0; nt < 8; nt++) {
        bf16x8 bf = *(const bf16x8*)(wp + nt * 2048);
        acc[nt] = __builtin_amdgcn_mfma_f32_16x16x32_bf16(af[ks], bf, acc[nt], 0, 0, 0);
      }
    }
    // per-wave tile: in-wave lgkmcnt ordering suffices, no barrier
#pragma unroll
    for (int nt = 0; nt < 8; nt++) {
      float be = benc[nt * 16 + col];
#pragma unroll
      for (int r = 0; r < 4; r++) {
        float v = acc[nt][r] + be;
        v = v > 0.f ? v : 0.01f * v;
        tl[(quad * 4 + r) * 136 + nt * 16 + col] = f2bf(v);
      }
    }
    bf16x8 a2[4];
#pragma unroll
    for (int ks = 0; ks < 4; ks++)
      a2[ks] = *(const bf16x8*)&tl[col * 136 + ks * 32 + quad * 8];

    f32x4 acc2[8];
#pragma unroll
    for (int nt = 0; nt < 8; nt++) acc2[nt] = zero;
#pragma unroll
    for (int ks = 0; ks < 4; ks++) {
      const u16* wp = Wmix + col * 128 + ks * 32 + quad * 8;
#pragma unroll
      for (int nt = 0; nt < 8; nt++) {
        bf16x8 bf = *(const bf16x8*)(wp + nt * 2048);
        acc2[nt] = __builtin_amdgcn_mfma_f32_16x16x32_bf16(a2[ks], bf, acc2[nt], 0, 0, 0);
      }
    }
#pragma unroll
    for (int nt = 0; nt < 8; nt++) {
      float bm = bmix ? bmix[nt * 16 + col] : 0.f;
#pragma unroll
      for (int r = 0; r < 4; r++)
        outp[(size_t)(row0 + quad * 4 + r) * 128 + nt * 16 + col] = f2bf(acc2[nt][r] + bm);
    }
  }
}

// ---------------------------------------------------------------------------
// out = msgX@Wrel^T + x@Wroot^T + brel + broot  (fp32 out), both types.
// ---------------------------------------------------------------------------
__global__ __launch_bounds__(256) void out_gemm2(
    const u16* __restrict__ xa_bf, const u16* __restrict__ xb_bf,
    const u16* __restrict__ msgX_a, const u16* __restrict__ msgX_b,
    const u16* __restrict__ Wrelba_b, const u16* __restrict__ Wrelab_b,
    const u16* __restrict__ Wrootba_b, const u16* __restrict__ Wrootab_b,
    const float* __restrict__ brel_ba, const float* __restrict__ broot_ba,
    const float* __restrict__ brel_ab, const float* __restrict__ broot_ab,
    float* __restrict__ out_a, float* __restrict__ out_b)
{
  int w = blockIdx.x * 4 + (threadIdx.x >> 6);
  int type = (w >= NBLK * 4) ? 1 : 0;
  int nw = w - type * NBLK * 4;
  if (nw >= NWAVES) return;
  const u16* xbf = type ? xb_bf : xa_bf;
  const u16* msg = type ? msgX_b : msgX_a;
  const u16* Wrel = type ? Wrelab_b : Wrelba_b;
  const u16* Wroot = type ? Wrootab_b : Wrootba_b;
  const float* brel = type ? brel_ab : brel_ba;
  const float* broot = type ? broot_ab : broot_ba;
  float* outp = type ? out_b : out_a;
  int row0 = nw * 16;
  int lane = threadIdx.x & 63;
  int col = lane & 15;
  int quad = lane >> 4;

  bf16x8 ax[4], am[4];
#pragma unroll
  for (int ks = 0; ks < 4; ks++) {
    ax[ks] = *(const bf16x8*)(xbf + (size_t)(row0 + col) * 128 + ks * 32 + quad * 8);
    am[ks] = *(const bf16x8*)(msg + (size_t)(row0 + col) * 128 + ks * 32 + quad * 8);
  }

  f32x4 zero = {0.f, 0.f, 0.f, 0.f};
  f32x4 acc[8];
#pragma unroll
  for (int nt = 0; nt < 8; nt++) acc[nt] = zero;
#pragma unroll
  for (int ks = 0; ks < 4; ks++) {
    const u16* wp1 = Wrel + col * 128 + ks * 32 + quad * 8;
    const u16* wp2 = Wroot + col * 128 + ks * 32 + quad * 8;
#pragma unroll
    for (int nt = 0; nt < 8; nt++) {
      bf16x8 b1f = *(const bf16x8*)(wp1 + nt * 2048);
      acc[nt] = __builtin_amdgcn_mfma_f32_16x16x32_bf16(am[ks], b1f, acc[nt], 0, 0, 0);
      bf16x8 b2f = *(const bf16x8*)(wp2 + nt * 2048);
      acc[nt] = __builtin_amdgcn_mfma_f32_16x16x32_bf16(ax[ks], b2f, acc[nt], 0, 0, 0);
    }
  }
#pragma unroll
  for (int nt = 0; nt < 8; nt++) {
    int c = nt * 16 + col;
    float b = brel[c] + broot[c];
#pragma unroll
    for (int r = 0; r < 4; r++)
      outp[(size_t)(row0 + quad * 4 + r) * 128 + c] = acc[nt][r] + b;
  }
}

// ---------------------------------------------------------------------------
// Persistent edge kernel over DST-BUCKET-SORTED edges, XCD-chunked:
// blocks with blockIdx&7 == k process the contiguous group chunk
// [k*CHG, (k+1)*CHG) — on MI355X's round-robin block->XCD dispatch each
// XCD's L2 then holds a ~0.9MB dst slice (x_d, v, msgX all L2-resident).
// Body = round-6 register-diet kernel (af-tile + t-tile, no barriers).
// ---------------------------------------------------------------------------
__global__ __launch_bounds__(256, 4) void edge_fused_p(
    const u16* __restrict__ xs, const u16* __restrict__ xd,
    const int* __restrict__ es, const int* __restrict__ ed,
    const u16* __restrict__ W1c,
    const u16* __restrict__ uT, const u16* __restrict__ vT,
    const float* __restrict__ W2, const float* __restrict__ b2p,
    u16* __restrict__ msgX)
{
  __shared__ u16 tld[4][2][2176];  // per wave: [0]=af tile, [1]=t tile
  int widx = threadIdx.x >> 6;
  int lane = threadIdx.x & 63;
  int col = lane & 15;
  int quad = lane >> 4;
  int e4 = lane >> 2;
  int c0 = (lane & 3) * 32;
  u16* tA = tld[widx][0];
  u16* tT = tld[widx][1];
  float b2v = b2p[0];

  int xcd = blockIdx.x & 7;
  int wix = (blockIdx.x >> 3) * 4 + widx;   // wave index within this xcd chunk
  const int wpx = (EPB >> 3) * 4;           // 1024 waves per chunk
  int gend = (xcd + 1) * CHG;
  if (gend > WPT) gend = WPT;

  for (int g = xcd * CHG + wix; g < gend; g += wpx) {
    int e0 = g * 16;

    int si = es[e0 + col];
    int di = ed[e0 + col];
    int s2 = es[e0 + e4];
    int d2 = ed[e0 + e4];

    // x gathers (col-layout) — feed the MFMA chain
    bf16x8 af[4], d8[4];
#pragma unroll
    for (int ks = 0; ks < 4; ks++) {
      af[ks] = *(const bf16x8*)(xs + (size_t)si * 128 + ks * 32 + quad * 8);
      d8[ks] = *(const bf16x8*)(xd + (size_t)di * 128 + ks * 32 + quad * 8);
    }

    // df = |par - cld|  (d8 dies here)
    bf16x8 df[4];
#pragma unroll
    for (int ks = 0; ks < 4; ks++)
#pragma unroll
      for (int j = 0; j < 8; j++)
        df[ks][j] = (short)f2bf(__builtin_fabsf(bfe(af[ks], j) - bfe(d8[ks], j)));

    // stage af -> af-tile EARLY (af dies; scatter reads it back from LDS)
#pragma unroll
    for (int ks = 0; ks < 4; ks++)
      *(bf16x8*)&tA[col * 136 + ks * 32 + quad * 8] = af[ks];

    // 32 MFMAs (t = d @ W1c^T)
    f32x4 zero = {0.f, 0.f, 0.f, 0.f};
    f32x4 acc[8];
#pragma unroll
    for (int nt = 0; nt < 8; nt++) acc[nt] = zero;
#pragma unroll
    for (int ks = 0; ks < 4; ks++) {
      const u16* wp = W1c + col * 128 + ks * 32 + quad * 8;
#pragma unroll
      for (int nt = 0; nt < 8; nt++) {
        bf16x8 bf = *(const bf16x8*)(wp + nt * 2048);
        acc[nt] = __builtin_amdgcn_mfma_f32_16x16x32_bf16(df[ks], bf, acc[nt], 0, 0, 0);
      }
    }

    // u/v gathers (edge-major) — TLP covers the latency
    const u16* urow = uT + (size_t)s2 * 128 + c0;
    const u16* vrow = vT + (size_t)d2 * 128 + c0;
    bf16x8 UU[4], VV[4];
#pragma unroll
    for (int k = 0; k < 4; k++) {
      UU[k] = *(const bf16x8*)(urow + k * 8);
      VV[k] = *(const bf16x8*)(vrow + k * 8);
    }

    // t -> t-tile (C-layout -> edge-major); acc dies here
#pragma unroll
    for (int nt = 0; nt < 8; nt++)
#pragma unroll
      for (int r = 0; r < 4; r++)
        tT[(quad * 4 + r) * 136 + nt * 16 + col] = f2bf(acc[nt][r]);

    // edge-major epilogue: w = sigmoid(W2 . relu(t + u + v) + b2)
    const u16* trow = &tT[e4 * 136 + c0];
    float p = 0.f;
#pragma unroll
    for (int k = 0; k < 4; k++) {
      bf16x8 tt = *(const bf16x8*)(trow + k * 8);
      f32x4 w0 = *(const f32x4*)(W2 + c0 + k * 8);
      f32x4 w1 = *(const f32x4*)(W2 + c0 + k * 8 + 4);
#pragma unroll
      for (int j = 0; j < 4; j++) {
        float q0 = bfe(tt, j) + bfe(UU[k], j) + bfe(VV[k], j);
        if (q0 > 0.f) p += q0 * w0[j];
        float q1 = bfe(tt, j + 4) + bfe(UU[k], j + 4) + bfe(VV[k], j + 4);
        if (q1 > 0.f) p += q1 * w1[j];
      }
    }
    p += __shfl_xor(p, 1, 64);
    p += __shfl_xor(p, 2, 64);
    float wgt = 1.f / (1.f + __expf(-(p + b2v)));

    // coalesced pk scatter from the af-tile (64B runs per dst row)
#pragma unroll
    for (int r = 0; r < 4; r++) {
      int src_lane = (quad * 4 + r) * 4;
      float wr = __shfl(wgt, src_lane, 64);
      int dr = __shfl(d2, src_lane, 64);
      u16* mrow = msgX + (size_t)dr * 128;
      const u16* xrow = &tA[(quad * 4 + r) * 136];
#pragma unroll
      for (int nt = 0; nt < 4; nt++) {
        int c = nt * 32 + col * 2;
        unsigned xv = *(const unsigned*)(xrow + c);
        pk_atomic_bf16(mrow + c, wr * bf2f((u16)(xv & 0xffff)),
                                 wr * bf2f((u16)(xv >> 16)));
      }
    }
  }
}

// ---------------------------------------------------------------------------
extern "C" void kernel_launch(void* const* d_in, const int* in_sizes, int n_in,
                              void* d_out, int out_size, void* d_ws, size_t ws_size,
                              hipStream_t stream) {
  const float* x_a      = (const float*)d_in[0];
  const float* x_b      = (const float*)d_in[1];
  const float* Wp       = (const float*)d_in[2];
  const float* bp       = (const float*)d_in[3];
  const float* Wc       = (const float*)d_in[4];
  const float* bc       = (const float*)d_in[5];
  const float* W1       = (const float*)d_in[6];
  const float* b1       = (const float*)d_in[7];
  const float* W2       = (const float*)d_in[8];
  const float* b2       = (const float*)d_in[9];
  const float* Wrel_ab  = (const float*)d_in[10];
  const float* brel_ab  = (const float*)d_in[11];
  const float* Wroot_ab = (const float*)d_in[12];
  const float* broot_ab = (const float*)d_in[13];
  const float* Wrel_ba  = (const float*)d_in[14];
  const float* brel_ba  = (const float*)d_in[15];
  const float* Wroot_ba = (const float*)d_in[16];
  const float* broot_ba = (const float*)d_in[17];
  const int*   ei_ab    = (const int*)d_in[18];
  const int*   ei_ba    = (const int*)d_in[19];

  char* ws = (char*)d_ws;
  u16* Wb        = (u16*)ws;               // 9*16384*2 B
  u16* Wp_b      = Wb + 0 * 16384;
  u16* Wc_b      = Wb + 1 * 16384;
  u16* W1a_b     = Wb + 2 * 16384;
  u16* W1b_b     = Wb + 3 * 16384;
  u16* W1c_b     = Wb + 4 * 16384;
  u16* Wrelab_b  = Wb + 5 * 16384;
  u16* Wrootab_b = Wb + 6 * 16384;
  u16* Wrelba_b  = Wb + 7 * 16384;
  u16* Wrootba_b = Wb + 8 * 16384;

  // 12.8 MB bf16 node tables
  u16* xa_bf   = (u16*)(ws + 1048576);
  u16* xb_bf   = (u16*)(ws + 13848576);
  u16* u_a     = (u16*)(ws + 26648576);
  u16* v_a     = (u16*)(ws + 39448576);
  u16* u_b     = (u16*)(ws + 52248576);
  u16* v_b     = (u16*)(ws + 65048576);
  u16* msgX_a  = (u16*)(ws + 77848576);    // contiguous pair, 25.6 MB total
  u16* msgX_b  = (u16*)(ws + 90648576);

  float* out_a = (float*)d_out;
  float* out_b = out_a + (size_t)N_NODES * 128;

  // sort scratch lives in d_out (fully overwritten by out_gemm2 at the end):
  //   es/ed arrays: 4 x 2MB at offset 0; counters/ptrs at 8MiB.
  int* es_ab = (int*)d_out;
  int* ed_ab = es_ab + EDGES;
  int* es_ba = ed_ab + EDGES;
  int* ed_ba = es_ba + EDGES;
  int* cnt   = (int*)((char*)d_out + 8388608);   // 2*NBUCK ints
  int* ptr   = cnt + 2 * NBUCK;                  // 2*NBUCK ints

  // 1. weights -> bf16 + msgX zeroing + counter zeroing
  prep_weights_zero<<<6827, 256, 0, stream>>>(Wp, Wc, W1, Wrel_ab, Wroot_ab,
                                              Wrel_ba, Wroot_ba, Wb, msgX_a, cnt);

  // 2. dst-bucket counting sort of both edge lists
  edge_hist<<<128, 256, 0, stream>>>(ei_ab, ei_ba, cnt);
  edge_scan<<<1, 1024, 0, stream>>>(cnt, ptr);
  edge_scatter_sort<<<1024, 256, 0, stream>>>(ei_ab, ei_ba, ptr,
                                              es_ab, ed_ab, es_ba, ed_ba);

  // 3. encoder + x fp32->bf16 cast fused
  encoder2<<<2 * NBLK, 256, 0, stream>>>(x_a, x_b, Wp_b, bp, Wc_b, bc,
                                         W1a_b, b1, W1b_b,
                                         xa_bf, xb_bf, u_a, v_a, u_b, v_b);

  // 4a. edge phase, type A->B (src=x_a, dst in B, msg into msgX_b)
  edge_fused_p<<<EPB, 256, 0, stream>>>(xa_bf, xb_bf, es_ab, ed_ab, W1c_b,
                                        u_a, v_b, W2, b2, msgX_b);

  // 4b. edge phase, type B->A (src=x_b, dst in A, msg into msgX_a)
  edge_fused_p<<<EPB, 256, 0, stream>>>(xb_bf, xa_bf, es_ba, ed_ba, W1c_b,
                                        u_b, v_a, W2, b2, msgX_a);

  // 5. output GEMM (overwrites the sort scratch in d_out)
  out_gemm2<<<2 * NBLK, 256, 0, stream>>>(xa_bf, xb_bf, msgX_a, msgX_b,
                                          Wrelba_b, Wrelab_b,
                                          Wrootba_b, Wrootab_b,
                                          brel_ba, broot_ba, brel_ab, broot_ab,
                                          out_a, out_b);
}

// Round 9
// 666.585 us; speedup vs baseline: 1.6826x; 1.6826x over previous
//
#include <hip/hip_runtime.h>
#include <hip/hip_bf16.h>

typedef unsigned short u16;
typedef __attribute__((ext_vector_type(8))) short bf16x8;
typedef __attribute__((ext_vector_type(2))) short s16x2;
typedef __attribute__((ext_vector_type(4))) float f32x4;

#define N_NODES 50000
#define EDGES 500000
#define WPT 31250     // 16-edge groups per type
#define EPB 2048      // persistent edge blocks per type-launch
#define EPW (EPB * 4) // persistent edge waves per type-launch (8192)
#define NWAVES 3125   // node waves per type (50000/16)
#define NBLK 782      // ceil(NWAVES/4)

__device__ __forceinline__ u16 f2bf(float f) {
  return __builtin_bit_cast(u16, __float2bfloat16(f));
}
__device__ __forceinline__ float bf2f(u16 u) {
  return __builtin_bit_cast(float, ((unsigned)u) << 16);
}
__device__ __forceinline__ float bfe(bf16x8 v, int j) {
  return bf2f((u16)v[j]);
}

// packed bf16 atomic add (2 values at 4B-aligned address)
__device__ __forceinline__ void pk_atomic_bf16(u16* addr, float lo, float hi) {
#if __has_builtin(__builtin_amdgcn_global_atomic_fadd_v2bf16)
  s16x2 v;
  v[0] = (short)f2bf(lo);
  v[1] = (short)f2bf(hi);
  __builtin_amdgcn_global_atomic_fadd_v2bf16(
      (__attribute__((address_space(1))) s16x2*)addr, v);
#else
  unsigned* p = (unsigned*)addr;
  unsigned old = *p, assumed;
  do {
    assumed = old;
    float l2 = bf2f((u16)(assumed & 0xffff)) + lo;
    float h2 = bf2f((u16)(assumed >> 16)) + hi;
    unsigned nv = (unsigned)f2bf(l2) | ((unsigned)f2bf(h2) << 16);
    old = atomicCAS(p, assumed, nv);
  } while (old != assumed);
#endif
}

// ---------------------------------------------------------------------------
// weights -> bf16 tables (9 x 128x128 row-major), PLUS msgX zeroing
// ---------------------------------------------------------------------------
__global__ __launch_bounds__(256) void prep_weights_zero(
    const float* __restrict__ Wp, const float* __restrict__ Wc,
    const float* __restrict__ W1,
    const float* __restrict__ Wrel_ab, const float* __restrict__ Wroot_ab,
    const float* __restrict__ Wrel_ba, const float* __restrict__ Wroot_ba,
    u16* __restrict__ out, u16* __restrict__ msg)
{
  if (blockIdx.x >= 576) {
    // zero 2 * N_NODES * 128 bf16 = 12.8M u16, 8 per thread, 6250 blocks
    size_t t = (size_t)(blockIdx.x - 576) * 256 + threadIdx.x;
    bf16x8 z = {0, 0, 0, 0, 0, 0, 0, 0};
    *(bf16x8*)(msg + t * 8) = z;
    return;
  }
  int tid = blockIdx.x * 256 + threadIdx.x;  // 9*16384
  int m = tid >> 14;
  int idx = tid & 16383;
  int r = idx >> 7;
  int c = idx & 127;
  float val;
  switch (m) {
    case 0: val = Wp[r * 128 + c]; break;
    case 1: val = Wc[r * 128 + c]; break;
    case 2: val = W1[r * 384 + c]; break;
    case 3: val = W1[r * 384 + 128 + c]; break;
    case 4: val = W1[r * 384 + 256 + c]; break;
    case 5: val = Wrel_ab[r * 128 + c]; break;
    case 6: val = Wroot_ab[r * 128 + c]; break;
    case 7: val = Wrel_ba[r * 128 + c]; break;
    default: val = Wroot_ba[r * 128 + c]; break;
  }
  out[tid] = f2bf(val);
}

// ---------------------------------------------------------------------------
// Fused encoder + x cast, both node sets in one dispatch (grid 2*NBLK):
//   u = lrelu(x@Wp^T+bp) @ W1a^T + b1   (b1 folded in)
//   v = lrelu(x@Wc^T+bc) @ W1b^T
// ---------------------------------------------------------------------------
__global__ __launch_bounds__(256) void encoder2(
    const float* __restrict__ xa, const float* __restrict__ xb,
    const u16* __restrict__ Wp_b, const float* __restrict__ bp,
    const u16* __restrict__ Wc_b, const float* __restrict__ bc,
    const u16* __restrict__ W1a_b, const float* __restrict__ b1,
    const u16* __restrict__ W1b_b,
    u16* __restrict__ xa_bf, u16* __restrict__ xb_bf,
    u16* __restrict__ u_a, u16* __restrict__ v_a,
    u16* __restrict__ u_b, u16* __restrict__ v_b)
{
  __shared__ u16 tile[4][2176];   // 16 x pitch 136 bf16, per wave
  int widx = threadIdx.x >> 6;
  int w = blockIdx.x * 4 + widx;         // 0 .. 2*4*NBLK-1
  int type = (w >= NBLK * 4) ? 1 : 0;
  int nw = w - type * NBLK * 4;
  if (nw >= NWAVES) nw = NWAVES - 1;     // clamp (dup work; per-wave tile, safe)
  const float* x = type ? xb : xa;
  u16* xbf_out = type ? xb_bf : xa_bf;
  u16* u_out = type ? u_b : u_a;
  u16* v_out = type ? v_b : v_a;
  int row0 = nw * 16;
  int lane = threadIdx.x & 63;
  int col = lane & 15;
  int quad = lane >> 4;
  u16* tl = tile[widx];

  bf16x8 af[4];
#pragma unroll
  for (int ks = 0; ks < 4; ks++) {
    const float* xp = x + (size_t)(row0 + col) * 128 + ks * 32 + quad * 8;
    f32x4 lo = *(const f32x4*)xp;
    f32x4 hi = *(const f32x4*)(xp + 4);
    bf16x8 o;
#pragma unroll
    for (int j = 0; j < 4; j++) {
      o[j]     = (short)f2bf(lo[j]);
      o[j + 4] = (short)f2bf(hi[j]);
    }
    af[ks] = o;
    *(bf16x8*)(xbf_out + (size_t)(row0 + col) * 128 + ks * 32 + quad * 8) = o;
  }

  f32x4 zero = {0.f, 0.f, 0.f, 0.f};

  for (int chain = 0; chain < 2; chain++) {
    const u16* Wenc = chain ? Wc_b : Wp_b;
    const float* benc = chain ? bc : bp;
    const u16* Wmix = chain ? W1b_b : W1a_b;
    const float* bmix = chain ? nullptr : b1;
    u16* outp = chain ? v_out : u_out;

    f32x4 acc[8];
#pragma unroll
    for (int nt = 0; nt < 8; nt++) acc[nt] = zero;
#pragma unroll
    for (int ks = 0; ks < 4; ks++) {
      const u16* wp = Wenc + col * 128 + ks * 32 + quad * 8;
#pragma unroll
      for (int nt = 0; nt < 8; nt++) {
        bf16x8 bf = *(const bf16x8*)(wp + nt * 2048);
        acc[nt] = __builtin_amdgcn_mfma_f32_16x16x32_bf16(af[ks], bf, acc[nt], 0, 0, 0);
      }
    }
    // per-wave tile: in-wave lgkmcnt ordering suffices, no barrier
#pragma unroll
    for (int nt = 0; nt < 8; nt++) {
      float be = benc[nt * 16 + col];
#pragma unroll
      for (int r = 0; r < 4; r++) {
        float v = acc[nt][r] + be;
        v = v > 0.f ? v : 0.01f * v;
        tl[(quad * 4 + r) * 136 + nt * 16 + col] = f2bf(v);
      }
    }
    bf16x8 a2[4];
#pragma unroll
    for (int ks = 0; ks < 4; ks++)
      a2[ks] = *(const bf16x8*)&tl[col * 136 + ks * 32 + quad * 8];

    f32x4 acc2[8];
#pragma unroll
    for (int nt = 0; nt < 8; nt++) acc2[nt] = zero;
#pragma unroll
    for (int ks = 0; ks < 4; ks++) {
      const u16* wp = Wmix + col * 128 + ks * 32 + quad * 8;
#pragma unroll
      for (int nt = 0; nt < 8; nt++) {
        bf16x8 bf = *(const bf16x8*)(wp + nt * 2048);
        acc2[nt] = __builtin_amdgcn_mfma_f32_16x16x32_bf16(a2[ks], bf, acc2[nt], 0, 0, 0);
      }
    }
#pragma unroll
    for (int nt = 0; nt < 8; nt++) {
      float bm = bmix ? bmix[nt * 16 + col] : 0.f;
#pragma unroll
      for (int r = 0; r < 4; r++)
        outp[(size_t)(row0 + quad * 4 + r) * 128 + nt * 16 + col] = f2bf(acc2[nt][r] + bm);
    }
  }
}

// ---------------------------------------------------------------------------
// out = msgX@Wrel^T + x@Wroot^T + brel + broot  (fp32 out), both types.
// ---------------------------------------------------------------------------
__global__ __launch_bounds__(256) void out_gemm2(
    const u16* __restrict__ xa_bf, const u16* __restrict__ xb_bf,
    const u16* __restrict__ msgX_a, const u16* __restrict__ msgX_b,
    const u16* __restrict__ Wrelba_b, const u16* __restrict__ Wrelab_b,
    const u16* __restrict__ Wrootba_b, const u16* __restrict__ Wrootab_b,
    const float* __restrict__ brel_ba, const float* __restrict__ broot_ba,
    const float* __restrict__ brel_ab, const float* __restrict__ broot_ab,
    float* __restrict__ out_a, float* __restrict__ out_b)
{
  int w = blockIdx.x * 4 + (threadIdx.x >> 6);
  int type = (w >= NBLK * 4) ? 1 : 0;
  int nw = w - type * NBLK * 4;
  if (nw >= NWAVES) return;
  const u16* xbf = type ? xb_bf : xa_bf;
  const u16* msg = type ? msgX_b : msgX_a;
  const u16* Wrel = type ? Wrelab_b : Wrelba_b;
  const u16* Wroot = type ? Wrootab_b : Wrootba_b;
  const float* brel = type ? brel_ab : brel_ba;
  const float* broot = type ? broot_ab : broot_ba;
  float* outp = type ? out_b : out_a;
  int row0 = nw * 16;
  int lane = threadIdx.x & 63;
  int col = lane & 15;
  int quad = lane >> 4;

  bf16x8 ax[4], am[4];
#pragma unroll
  for (int ks = 0; ks < 4; ks++) {
    ax[ks] = *(const bf16x8*)(xbf + (size_t)(row0 + col) * 128 + ks * 32 + quad * 8);
    am[ks] = *(const bf16x8*)(msg + (size_t)(row0 + col) * 128 + ks * 32 + quad * 8);
  }

  f32x4 zero = {0.f, 0.f, 0.f, 0.f};
  f32x4 acc[8];
#pragma unroll
  for (int nt = 0; nt < 8; nt++) acc[nt] = zero;
#pragma unroll
  for (int ks = 0; ks < 4; ks++) {
    const u16* wp1 = Wrel + col * 128 + ks * 32 + quad * 8;
    const u16* wp2 = Wroot + col * 128 + ks * 32 + quad * 8;
#pragma unroll
    for (int nt = 0; nt < 8; nt++) {
      bf16x8 b1f = *(const bf16x8*)(wp1 + nt * 2048);
      acc[nt] = __builtin_amdgcn_mfma_f32_16x16x32_bf16(am[ks], b1f, acc[nt], 0, 0, 0);
      bf16x8 b2f = *(const bf16x8*)(wp2 + nt * 2048);
      acc[nt] = __builtin_amdgcn_mfma_f32_16x16x32_bf16(ax[ks], b2f, acc[nt], 0, 0, 0);
    }
  }
#pragma unroll
  for (int nt = 0; nt < 8; nt++) {
    int c = nt * 16 + col;
    float b = brel[c] + broot[c];
#pragma unroll
    for (int r = 0; r < 4; r++)
      outp[(size_t)(row0 + quad * 4 + r) * 128 + c] = acc[nt][r] + b;
  }
}

// ---------------------------------------------------------------------------
// Persistent TYPE-COHERENT fused edge kernel, round-4 body + in-wave
// cross-iteration software pipeline (resubmission of round-8's experiment;
// audit found no OOB/termination/uninit defects; prior failure attributed
// to infra). Hardening: no early return — single control path for all waves.
//   * next group's ei + x-row gathers are issued before the epilogue/scatter
//     of the current group (latency hides under VALU tail + atomic issue).
//   * asm memory fence pins the prefetch above the scatter.
//   * no __launch_bounds__ min: VGPR free to land ~200 (2 waves/SIMD >=
//     measured r4 residency, so concurrency & traffic regime unchanged).
// ---------------------------------------------------------------------------
__global__ __launch_bounds__(256) void edge_fused_p(
    const u16* __restrict__ xs, const u16* __restrict__ xd,
    const int* __restrict__ ei,
    const u16* __restrict__ W1c,
    const u16* __restrict__ uT, const u16* __restrict__ vT,
    const float* __restrict__ W2, const float* __restrict__ b2p,
    u16* __restrict__ msgX)
{
  __shared__ u16 tld[4][2176];   // 16 x pitch 136 bf16, per wave (17.4 KB)
  int widx = threadIdx.x >> 6;
  int wt = blockIdx.x * 4 + widx;   // 0..EPW-1 (EPW=8192 < WPT always)
  int lane = threadIdx.x & 63;
  int col = lane & 15;
  int quad = lane >> 4;
  int e4 = lane >> 2;
  int c0 = (lane & 3) * 32;
  u16* tl = tld[widx];
  float b2v = b2p[0];

  int g = wt;

  // ---- prologue: stage group g (ei + x gathers) ----
  int s2, d2;
  bf16x8 af[4], d8[4];
  {
    int e0 = g * 16;
    int si = ei[e0 + col];
    int di = ei[EDGES + e0 + col];
    s2 = ei[e0 + e4];
    d2 = ei[EDGES + e0 + e4];
#pragma unroll
    for (int ks = 0; ks < 4; ks++) {
      af[ks] = *(const bf16x8*)(xs + (size_t)si * 128 + ks * 32 + quad * 8);
      d8[ks] = *(const bf16x8*)(xd + (size_t)di * 128 + ks * 32 + quad * 8);
    }
  }

  while (g < WPT) {
    // 1. u/v gathers for CURRENT group (consumed in epilogue)
    const u16* urow = uT + (size_t)s2 * 128 + c0;
    const u16* vrow = vT + (size_t)d2 * 128 + c0;
    bf16x8 UU[4], VV[4];
#pragma unroll
    for (int k = 0; k < 4; k++) {
      UU[k] = *(const bf16x8*)(urow + k * 8);
      VV[k] = *(const bf16x8*)(vrow + k * 8);
    }

    // 2. NEXT group's edge ids (issue early)
    int gn = g + EPW;
    bool hasn = gn < WPT;
    int sin = 0, din = 0, s2n = 0, d2n = 0;
    if (hasn) {
      int e0n = gn * 16;
      sin = ei[e0n + col];
      din = ei[EDGES + e0n + col];
      s2n = ei[e0n + e4];
      d2n = ei[EDGES + e0n + e4];
    }

    // 3. df = |par - cld| (d8 dies here)
    bf16x8 df[4];
#pragma unroll
    for (int ks = 0; ks < 4; ks++)
#pragma unroll
      for (int j = 0; j < 8; j++)
        df[ks][j] = (short)f2bf(__builtin_fabsf(bfe(af[ks], j) - bfe(d8[ks], j)));

    // 4. 32 MFMAs (t = d @ W1c^T)
    f32x4 zero = {0.f, 0.f, 0.f, 0.f};
    f32x4 acc[8];
#pragma unroll
    for (int nt = 0; nt < 8; nt++) acc[nt] = zero;
#pragma unroll
    for (int ks = 0; ks < 4; ks++) {
      const u16* wp = W1c + col * 128 + ks * 32 + quad * 8;
#pragma unroll
      for (int nt = 0; nt < 8; nt++) {
        bf16x8 bf = *(const bf16x8*)(wp + nt * 2048);
        acc[nt] = __builtin_amdgcn_mfma_f32_16x16x32_bf16(df[ks], bf, acc[nt], 0, 0, 0);
      }
    }

    // 5. PREFETCH next group's x rows — issued before the scatter atomics
    bf16x8 AFn[4], BDn[4];
    if (hasn) {
#pragma unroll
      for (int ks = 0; ks < 4; ks++) {
        AFn[ks] = *(const bf16x8*)(xs + (size_t)sin * 128 + ks * 32 + quad * 8);
        BDn[ks] = *(const bf16x8*)(xd + (size_t)din * 128 + ks * 32 + quad * 8);
      }
    }
    // fence: prefetch loads may not sink below this point (past the atomics)
    asm volatile("" ::: "memory");

    // 6. t -> tile (C-layout -> edge-major); acc dies here
#pragma unroll
    for (int nt = 0; nt < 8; nt++)
#pragma unroll
      for (int r = 0; r < 4; r++)
        tl[(quad * 4 + r) * 136 + nt * 16 + col] = f2bf(acc[nt][r]);

    // 7. edge-major epilogue: w = sigmoid(W2 . relu(t + u + v) + b2)
    const u16* trow = &tl[e4 * 136 + c0];
    float p = 0.f;
#pragma unroll
    for (int k = 0; k < 4; k++) {
      bf16x8 tt = *(const bf16x8*)(trow + k * 8);
      f32x4 w0 = *(const f32x4*)(W2 + c0 + k * 8);
      f32x4 w1 = *(const f32x4*)(W2 + c0 + k * 8 + 4);
#pragma unroll
      for (int j = 0; j < 4; j++) {
        float q0 = bfe(tt, j) + bfe(UU[k], j) + bfe(VV[k], j);
        if (q0 > 0.f) p += q0 * w0[j];
        float q1 = bfe(tt, j + 4) + bfe(UU[k], j + 4) + bfe(VV[k], j + 4);
        if (q1 > 0.f) p += q1 * w1[j];
      }
    }
    p += __shfl_xor(p, 1, 64);
    p += __shfl_xor(p, 2, 64);
    float wgt = 1.f / (1.f + __expf(-(p + b2v)));

    // 8. af -> same per-wave tile (t reads above are in-wave ordered),
    //    then coalesced pk scatter (64B runs per dst row)
#pragma unroll
    for (int ks = 0; ks < 4; ks++)
      *(bf16x8*)&tl[col * 136 + ks * 32 + quad * 8] = af[ks];
#pragma unroll
    for (int r = 0; r < 4; r++) {
      int src_lane = (quad * 4 + r) * 4;
      float wr = __shfl(wgt, src_lane, 64);
      int dr = __shfl(d2, src_lane, 64);
      u16* mrow = msgX + (size_t)dr * 128;
      const u16* xrow = &tl[(quad * 4 + r) * 136];
#pragma unroll
      for (int nt = 0; nt < 4; nt++) {
        int c = nt * 32 + col * 2;
        unsigned xv = *(const unsigned*)(xrow + c);
        pk_atomic_bf16(mrow + c, wr * bf2f((u16)(xv & 0xffff)),
                                 wr * bf2f((u16)(xv >> 16)));
      }
    }

    // 9. rotate pipeline registers
    if (hasn) {
#pragma unroll
      for (int ks = 0; ks < 4; ks++) { af[ks] = AFn[ks]; d8[ks] = BDn[ks]; }
      s2 = s2n;
      d2 = d2n;
    }
    g = gn;
  }
}

// ---------------------------------------------------------------------------
extern "C" void kernel_launch(void* const* d_in, const int* in_sizes, int n_in,
                              void* d_out, int out_size, void* d_ws, size_t ws_size,
                              hipStream_t stream) {
  const float* x_a      = (const float*)d_in[0];
  const float* x_b      = (const float*)d_in[1];
  const float* Wp       = (const float*)d_in[2];
  const float* bp       = (const float*)d_in[3];
  const float* Wc       = (const float*)d_in[4];
  const float* bc       = (const float*)d_in[5];
  const float* W1       = (const float*)d_in[6];
  const float* b1       = (const float*)d_in[7];
  const float* W2       = (const float*)d_in[8];
  const float* b2       = (const float*)d_in[9];
  const float* Wrel_ab  = (const float*)d_in[10];
  const float* brel_ab  = (const float*)d_in[11];
  const float* Wroot_ab = (const float*)d_in[12];
  const float* broot_ab = (const float*)d_in[13];
  const float* Wrel_ba  = (const float*)d_in[14];
  const float* brel_ba  = (const float*)d_in[15];
  const float* Wroot_ba = (const float*)d_in[16];
  const float* broot_ba = (const float*)d_in[17];
  const int*   ei_ab    = (const int*)d_in[18];
  const int*   ei_ba    = (const int*)d_in[19];

  char* ws = (char*)d_ws;
  u16* Wb        = (u16*)ws;               // 9*16384*2 B
  u16* Wp_b      = Wb + 0 * 16384;
  u16* Wc_b      = Wb + 1 * 16384;
  u16* W1a_b     = Wb + 2 * 16384;
  u16* W1b_b     = Wb + 3 * 16384;
  u16* W1c_b     = Wb + 4 * 16384;
  u16* Wrelab_b  = Wb + 5 * 16384;
  u16* Wrootab_b = Wb + 6 * 16384;
  u16* Wrelba_b  = Wb + 7 * 16384;
  u16* Wrootba_b = Wb + 8 * 16384;

  // 12.8 MB bf16 node tables
  u16* xa_bf   = (u16*)(ws + 1048576);
  u16* xb_bf   = (u16*)(ws + 13848576);
  u16* u_a     = (u16*)(ws + 26648576);
  u16* v_a     = (u16*)(ws + 39448576);
  u16* u_b     = (u16*)(ws + 52248576);
  u16* v_b     = (u16*)(ws + 65048576);
  u16* msgX_a  = (u16*)(ws + 77848576);    // contiguous pair, 25.6 MB total
  u16* msgX_b  = (u16*)(ws + 90648576);

  float* out_a = (float*)d_out;
  float* out_b = out_a + (size_t)N_NODES * 128;

  // 1. weights -> bf16 + msgX zeroing (576 weight blocks + 6250 zero blocks)
  prep_weights_zero<<<6826, 256, 0, stream>>>(Wp, Wc, W1, Wrel_ab, Wroot_ab,
                                              Wrel_ba, Wroot_ba, Wb, msgX_a);

  // 2. encoder + x fp32->bf16 cast fused
  encoder2<<<2 * NBLK, 256, 0, stream>>>(x_a, x_b, Wp_b, bp, Wc_b, bc,
                                         W1a_b, b1, W1b_b,
                                         xa_bf, xb_bf, u_a, v_a, u_b, v_b);

  // 3a. edge phase, type A->B (src=x_a, dst in B, msg into msgX_b)
  edge_fused_p<<<EPB, 256, 0, stream>>>(xa_bf, xb_bf, ei_ab, W1c_b,
                                        u_a, v_b, W2, b2, msgX_b);

  // 3b. edge phase, type B->A (src=x_b, dst in A, msg into msgX_a)
  edge_fused_p<<<EPB, 256, 0, stream>>>(xb_bf, xa_bf, ei_ba, W1c_b,
                                        u_b, v_a, W2, b2, msgX_a);

  // 4. output GEMM
  out_gemm2<<<2 * NBLK, 256, 0, stream>>>(xa_bf, xb_bf, msgX_a, msgX_b,
                                          Wrelba_b, Wrelab_b,
                                          Wrootba_b, Wrootab_b,
                                          brel_ba, broot_ba, brel_ab, broot_ab,
                                          out_a, out_b);
}